// Round 2
// baseline (1042.576 us; speedup 1.0000x reference)
//
#include <hip/hip_runtime.h>

// Gaussian blur (theta=3, truncate=4 -> r=12, 25 taps), separable, minus identity.
// src: (4, 512, 512, 21) fp32 NHWC.  out = V(H(src)) - src with zero padding.
// Pass 1: vertical conv -> fp16 intermediate (NHWC flat) in d_ws (44 MB).
//         Streaming ring: thread owns 2 cols, walks BH=32 rows with a ring of
//         25 partial accumulators (50 VGPRs, bounded regardless of BH).
//         All ring indices compile-time (fixed 56-step full unroll).
// Pass 2: one block per row; LDS channel-planar transpose; 25-tap conv from LDS
//         with aligned b32 reads; LDS re-transpose; coalesced float4 out.

#define BATCH 4
#define HH 512
#define WW 512
#define CC 21
#define WC (WW * CC)            // 10752 floats per row
#define IMG ((size_t)HH * WC)   // elems per batch image
#define RAD 12

// g(d) = exp(-d^2/18), index = d + 12 (symmetric)
__device__ static constexpr float GW[25] = {
    3.3546263e-04f, 1.2038700e-03f, 3.8659300e-03f, 1.1108997e-02f, 2.8565500e-02f,
    6.5728500e-02f, 1.3533528e-01f, 2.4935221e-01f, 4.1111229e-01f, 6.0653066e-01f,
    8.0073740e-01f, 9.4595947e-01f, 1.0000000e+00f, 9.4595947e-01f, 8.0073740e-01f,
    6.0653066e-01f, 4.1111229e-01f, 2.4935221e-01f, 1.3533528e-01f, 6.5728500e-02f,
    2.8565500e-02f, 1.1108997e-02f, 3.8659300e-03f, 1.2038700e-03f, 3.3546263e-04f
};

// ---------------- Pass 1: vertical (streaming ring) ----------------
// 256 threads; thread owns 2 consecutive flat cols (float2) x BH output rows.
// Ring of 25 accumulators; output l lives in slot l%25, stored+zeroed at
// step st = l+24, slot reused by output l+25 starting at step l+25.
constexpr int BH = 32;
constexpr int NS = BH + 2 * RAD;   // 56 load steps

__global__ __launch_bounds__(256)
void vconv_kernel(const float* __restrict__ src, _Float16* __restrict__ v)
{
    const int f  = blockIdx.x * 512 + threadIdx.x * 2;    // flat col; 21*512 = WC exact
    const int i0 = blockIdx.y * BH;                       // first output row
    const int b  = blockIdx.z;

    const float* s  = src + (size_t)b * IMG + f;
    _Float16*    vp = v   + (size_t)b * IMG + f;

    float acc[25][2];
#pragma unroll
    for (int q = 0; q < 25; ++q) { acc[q][0] = 0.f; acc[q][1] = 0.f; }

#pragma unroll
    for (int st = 0; st < NS; ++st) {
        const int r = i0 - RAD + st;                      // loaded src row
        float2 x = make_float2(0.f, 0.f);
        if ((unsigned)r < (unsigned)HH)
            x = *(const float2*)(s + (size_t)r * WC);

#pragma unroll
        for (int t = 0; t < 25; ++t) {
            const int l = st - 2 * RAD + t;               // output local row (const)
            if (l >= 0 && l < BH) {
                const int q = l % 25;                     // compile-time slot
                const float w = GW[24 - t];               // literal (symmetric)
                acc[q][0] = fmaf(w, x.x, acc[q][0]);
                acc[q][1] = fmaf(w, x.y, acc[q][1]);
            }
        }

        if (st >= 2 * RAD) {                              // output l complete
            const int l = st - 2 * RAD;
            const int q = l % 25;
            union { _Float16 h[2]; unsigned int u; } pk;
            pk.h[0] = (_Float16)acc[q][0];
            pk.h[1] = (_Float16)acc[q][1];
            *(unsigned int*)(vp + (size_t)(i0 + l) * WC) = pk.u;  // 4B aligned
            acc[q][0] = 0.f; acc[q][1] = 0.f;             // recycle slot
        }
    }
}

// ---------------- Pass 2: horizontal + subtract ----------------
// One block (384 threads) per (batch, row).
// LDS phase A: v row staged channel-planar: v_d[c][jd], jd = dword (2 fp16),
//   row stride 273 dwords (odd -> conflict-free), fp16 index = 16 + j
//   (16 zero-pad halves each side absorb the j<0 / j>=512 taps).
// Compute: thread (c, j0=32*jg) reads 28 aligned dwords, 800 literal-weight FMAs.
// LDS phase B: results re-staged NHWC fp32 (aliased buffer), then coalesced
//   float4 read + src subtract + store.
constexpr int SD  = 273;   // dword stride per channel row in LDS
constexpr int NT2 = 384;

__global__ __launch_bounds__(NT2)
void hconv_kernel(const _Float16* __restrict__ v, const float* __restrict__ src,
                  float* __restrict__ out)
{
    __shared__ float out_l[WC];                 // 43008 B
    unsigned int* v_d = (unsigned int*)out_l;   // alias; uses 21*273*4 = 22932 B

    const int tid = threadIdx.x;
    const int row = blockIdx.x;
    const int b   = blockIdx.y;
    const size_t rowbase = ((size_t)b * HH + row) * WC;

    // ---- phase A: zero pads + stage v row transposed ----
    if (tid < 21 * 17) {                        // 17 pad dwords per channel
        const int c = tid / 17, m = tid % 17;
        const int jd = (m < 8) ? m : (256 + m); // dwords [0..7] and [264..272]
        v_d[c * SD + jd] = 0u;
    }
    {
        const unsigned int* vrow32 = (const unsigned int*)(v + rowbase);
        _Float16* vh = (_Float16*)v_d;
#pragma unroll
        for (int k = 0; k < 14; ++k) {
            const int g = tid + k * NT2;        // 384*14 = 5376 dwords exactly
            union { unsigned int u; _Float16 h[2]; } cv;
            cv.u = vrow32[g];
            const int f0 = 2 * g;
            const int c0 = f0 % CC, j0 = f0 / CC;
            const int f1 = f0 + 1;
            const int c1 = f1 % CC, j1 = f1 / CC;
            vh[c0 * (2 * SD) + 16 + j0] = cv.h[0];
            vh[c1 * (2 * SD) + 16 + j1] = cv.h[1];
        }
    }
    __syncthreads();

    // ---- compute: 336 active threads, each (c, j0..j0+31) ----
    float res[32];
    const bool active = tid < 21 * 16;
    int c = 0, j0 = 0;
    if (active) {
        c  = tid % CC;
        j0 = (tid / CC) * 32;
        const int base = c * SD + (j0 + 4) / 2;  // dword of fp16 idx (16+j0-12)
        float w[56];
#pragma unroll
        for (int m = 0; m < 28; ++m) {
            union { unsigned int u; _Float16 h[2]; } cv;
            cv.u = v_d[base + m];
            w[2 * m]     = (float)cv.h[0];
            w[2 * m + 1] = (float)cv.h[1];
        }
#pragma unroll
        for (int k = 0; k < 32; ++k) {
            float a = 0.f;
#pragma unroll
            for (int t = 0; t < 25; ++t)
                a = fmaf(GW[t], w[k + t], a);
            res[k] = a;
        }
    }
    __syncthreads();

    // ---- phase B: re-stage NHWC fp32 (overwrites v_d region) ----
    if (active) {
#pragma unroll
        for (int k = 0; k < 32; ++k)
            out_l[(j0 + k) * CC + c] = res[k];
    }
    __syncthreads();

    // ---- final: coalesced subtract + store ----
    const float4* srcv = (const float4*)(src + rowbase);
    float4*       outv = (float4*)(out + rowbase);
    const float4* olv  = (const float4*)out_l;
#pragma unroll
    for (int k = 0; k < 7; ++k) {               // 384*7 = 2688 float4 exactly
        const int g = tid + k * NT2;
        const float4 o = olv[g];
        const float4 s = srcv[g];
        outv[g] = make_float4(o.x - s.x, o.y - s.y, o.z - s.z, o.w - s.w);
    }
}

extern "C" void kernel_launch(void* const* d_in, const int* in_sizes, int n_in,
                              void* d_out, int out_size, void* d_ws, size_t ws_size,
                              hipStream_t stream)
{
    const float* src = (const float*)d_in[0];
    float*       out = (float*)d_out;
    _Float16*    v   = (_Float16*)d_ws;     // 4*512*10752*2 = 44 MB

    dim3 g1(21, HH / BH, BATCH);            // 21 col-tiles, 16 row bands, 4 batches
    vconv_kernel<<<g1, 256, 0, stream>>>(src, v);

    dim3 g2(HH, BATCH);                     // one block per (row, batch)
    hconv_kernel<<<g2, NT2, 0, stream>>>(v, src, out);
}

// Round 4
// 408.733 us; speedup vs baseline: 2.5508x; 2.5508x over previous
//
#include <hip/hip_runtime.h>

// Gaussian blur (theta=3, truncate=4 -> r=12, 25 taps), separable, minus identity.
// src: (4, 512, 512, 21) fp32 NHWC.  out = V(H(src)) - src with zero padding.
// FUSED single kernel: block = (band of BH=4 output rows) x full width x 1 batch.
//   Phase V: register accumulation acc[4][12] over 28 unrolled input rows
//            (proven round-0 unroll scale), staged to LDS fp16 channel-planar.
//   Phase H: 25-tap conv from LDS, 16 outputs/thread x 3 reps (2688 items exact)
//            -> peak live regs ~100, under the 128-VGPR cap of 14 waves/CU.
//   Per-row: LDS re-transpose (aliased) -> coalesced float4 subtract+store.
// No global intermediate: HBM traffic = src once + out once (~176 MB).
// XCD-chunked band mapping: each XCD owns 64 contiguous bands -> the 7x
// vertical halo re-reads are served by that XCD's own L2.

#define BATCH 4
#define HH 512
#define WW 512
#define CC 21
#define WC (WW * CC)            // 10752 floats per row
#define IMG ((size_t)HH * WC)   // elems per batch image
#define RAD 12

// g(d) = exp(-d^2/18), index = d + 12 (symmetric)
__device__ static constexpr float GW[25] = {
    3.3546263e-04f, 1.2038700e-03f, 3.8659300e-03f, 1.1108997e-02f, 2.8565500e-02f,
    6.5728500e-02f, 1.3533528e-01f, 2.4935221e-01f, 4.1111229e-01f, 6.0653066e-01f,
    8.0073740e-01f, 9.4595947e-01f, 1.0000000e+00f, 9.4595947e-01f, 8.0073740e-01f,
    6.0653066e-01f, 4.1111229e-01f, 2.4935221e-01f, 1.3533528e-01f, 6.5728500e-02f,
    2.8565500e-02f, 1.1108997e-02f, 3.8659300e-03f, 1.2038700e-03f, 3.3546263e-04f
};

constexpr int BH  = 4;            // output rows per block
constexpr int NT  = 896;          // threads (14 waves); 896*3 float4 = 2688 = WC/4
constexpr int SD  = 273;          // dwords per channel plane (odd -> conflict-free)
constexpr int SDR = CC * SD;      // 5733 dwords per staged row
constexpr int NSV = BH + 2 * RAD; // 28 input rows per band
constexpr int HPT = 16;           // H outputs per thread
constexpr int NHREP = 3;          // 4 rows * 672 items = 2688 = 3 * 896

__global__ __launch_bounds__(NT)
void fused_kernel(const float* __restrict__ src, float* __restrict__ out)
{
    __shared__ unsigned int v_d[BH * SDR];   // 91728 B staged V rows (fp16)
    float* out_l = (float*)v_d;              // alias: fp32 out staging (43008 B),
                                             // used only after all H reads done

    const int tid = threadIdx.x;

    // XCD-chunked band mapping (512 blocks, 8 XCDs, 64 bands each)
    const int bid  = blockIdx.x;
    const int lin  = (bid & 7) * 64 + (bid >> 3);
    const int b    = lin >> 7;               // batch
    const int i0   = (lin & 127) * BH;       // first output row of band
    const float* sb = src + (size_t)b * IMG;

    // ---- zero pads: BH * 21 * 17 = 1428 pad dwords ----
#pragma unroll
    for (int rep = 0; rep < 2; ++rep) {
        const int item = tid + rep * NT;
        if (item < BH * 21 * 17) {
            const int rowp = item / 357;     // 21*17
            const int m    = item % 357;
            const int c    = m / 17, mm = m % 17;
            const int jd   = (mm < 8) ? mm : (256 + mm);
            v_d[rowp * SDR + c * SD + jd] = 0u;
        }
    }

    // ---- Phase V: vertical conv into registers ----
    // thread owns 3 float4 chunks at flat cols 4*tid + 3584*cch
    float acc[BH][12];
#pragma unroll
    for (int l = 0; l < BH; ++l)
#pragma unroll
        for (int e = 0; e < 12; ++e) acc[l][e] = 0.f;

#pragma unroll
    for (int st = 0; st < NSV; ++st) {
        const int r = i0 - RAD + st;
        float4 x0 = make_float4(0.f, 0.f, 0.f, 0.f);
        float4 x1 = x0, x2 = x0;
        if ((unsigned)r < (unsigned)HH) {
            const float* srow = sb + (size_t)r * WC + 4 * tid;
            x0 = *(const float4*)(srow);
            x1 = *(const float4*)(srow + 3584);
            x2 = *(const float4*)(srow + 7168);
        }
#pragma unroll
        for (int l = 0; l < BH; ++l) {
            const int t = st - l;
            if (t >= 0 && t <= 2 * RAD) {
                const float w = GW[t];       // compile-time literal
                acc[l][0]  = fmaf(w, x0.x, acc[l][0]);
                acc[l][1]  = fmaf(w, x0.y, acc[l][1]);
                acc[l][2]  = fmaf(w, x0.z, acc[l][2]);
                acc[l][3]  = fmaf(w, x0.w, acc[l][3]);
                acc[l][4]  = fmaf(w, x1.x, acc[l][4]);
                acc[l][5]  = fmaf(w, x1.y, acc[l][5]);
                acc[l][6]  = fmaf(w, x1.z, acc[l][6]);
                acc[l][7]  = fmaf(w, x1.w, acc[l][7]);
                acc[l][8]  = fmaf(w, x2.x, acc[l][8]);
                acc[l][9]  = fmaf(w, x2.y, acc[l][9]);
                acc[l][10] = fmaf(w, x2.z, acc[l][10]);
                acc[l][11] = fmaf(w, x2.w, acc[l][11]);
            }
        }
    }

    // ---- stage V rows into LDS fp16 channel-planar ----
    {
        _Float16* vh = (_Float16*)v_d;
#pragma unroll
        for (int cch = 0; cch < 3; ++cch) {
#pragma unroll
            for (int e = 0; e < 4; ++e) {
                const int ff = 4 * tid + 3584 * cch + e;
                const int ch = ff % CC, j = ff / CC;
                const int ofs = ch * (2 * SD) + 16 + j;
#pragma unroll
                for (int l = 0; l < BH; ++l)
                    vh[l * (2 * SDR) + ofs] = (_Float16)acc[l][4 * cch + e];
            }
        }
    }
    __syncthreads();

    // ---- Phase H: 25-tap conv from LDS; 16 outputs/thread, 3 reps ----
    // item = tid + rep*NT in [0, 2688): row = item/672, c = rem%21, j0 = (rem/21)*16
    float res[NHREP][HPT];
    int hrow[NHREP], hc[NHREP], hj0[NHREP];
#pragma unroll
    for (int rep = 0; rep < NHREP; ++rep) {
        const int item = tid + rep * NT;
        const int row  = item / 672;
        const int rem  = item % 672;
        const int c    = rem % CC;
        const int j0   = (rem / CC) * HPT;
        hrow[rep] = row; hc[rep] = c; hj0[rep] = j0;
        // first tap fp16 idx = 16 + j0 - 12 = j0 + 4 (even); 40 halves = 20 dwords
        const unsigned int* vb = v_d + row * SDR + c * SD + (j0 + 4) / 2;
        float w[40];
#pragma unroll
        for (int m = 0; m < 20; ++m) {
            union { unsigned int u; _Float16 h[2]; } cv;
            cv.u = vb[m];
            w[2 * m]     = (float)cv.h[0];
            w[2 * m + 1] = (float)cv.h[1];
        }
#pragma unroll
        for (int k = 0; k < HPT; ++k) {
            float a = 0.f;
#pragma unroll
            for (int t = 0; t < 25; ++t)
                a = fmaf(GW[t], w[k + t], a);
            res[rep][k] = a;
        }
    }
    __syncthreads();   // all H reads of v_d complete; safe to alias as out_l

    // ---- per-row: re-stage NHWC fp32, then coalesced subtract + store ----
#pragma unroll
    for (int rr = 0; rr < BH; ++rr) {
#pragma unroll
        for (int rep = 0; rep < NHREP; ++rep) {
            if (hrow[rep] == rr) {
#pragma unroll
                for (int k = 0; k < HPT; ++k)
                    out_l[(hj0[rep] + k) * CC + hc[rep]] = res[rep][k];
            }
        }
        __syncthreads();

        const size_t rowbase = ((size_t)b * HH + i0 + rr) * WC;
        const float4* srcv = (const float4*)(src + rowbase);
        float4*       outv = (float4*)(out + rowbase);
        const float4* olv  = (const float4*)out_l;
#pragma unroll
        for (int k2 = 0; k2 < 3; ++k2) {    // 896*3 = 2688 float4 exactly
            const int g = tid + k2 * NT;
            const float4 o = olv[g];
            const float4 s = srcv[g];
            outv[g] = make_float4(o.x - s.x, o.y - s.y, o.z - s.z, o.w - s.w);
        }
        __syncthreads();   // out_l free before next row's staging
    }
}

extern "C" void kernel_launch(void* const* d_in, const int* in_sizes, int n_in,
                              void* d_out, int out_size, void* d_ws, size_t ws_size,
                              hipStream_t stream)
{
    const float* src = (const float*)d_in[0];
    float*       out = (float*)d_out;
    (void)d_ws; (void)ws_size;

    dim3 g(HH / BH * BATCH);                // 512 blocks, batch folded in
    fused_kernel<<<g, NT, 0, stream>>>(src, out);
}

// Round 5
// 408.489 us; speedup vs baseline: 2.5523x; 1.0006x over previous
//
#include <hip/hip_runtime.h>

// Gaussian blur (theta=3, truncate=4 -> r=12, 25 taps), separable, minus identity.
// src: (4, 512, 512, 21) fp32 NHWC.  out = V(H(src)) - src with zero padding.
// FUSED single kernel: block = (band of BH=4 output rows) x full width x 1 batch.
//   Phase V: register accumulation acc[4][12] over 28 unrolled input rows
//            (proven round-0 unroll scale), staged to LDS fp16 channel-planar.
//   Phase H: row-by-row; 672 threads compute 16 outputs each and write them
//            IMMEDIATELY to a separate LDS out_row buffer (no alias, no
//            cross-barrier register residency -> no spill), then all 896
//            threads do the coalesced float4 subtract+store for that row.
// LDS: v_d 91728 B + out_row 43008 B = 134736 B (1 block/CU, 14 waves).
// No global intermediate: HBM traffic = src once + out once (~176 MB).
// XCD-chunked band mapping: each XCD owns 64 contiguous bands -> vertical
// halo re-reads served by that XCD's own L2.

#define BATCH 4
#define HH 512
#define WW 512
#define CC 21
#define WC (WW * CC)            // 10752 floats per row
#define IMG ((size_t)HH * WC)   // elems per batch image
#define RAD 12

// g(d) = exp(-d^2/18), index = d + 12 (symmetric)
__device__ static constexpr float GW[25] = {
    3.3546263e-04f, 1.2038700e-03f, 3.8659300e-03f, 1.1108997e-02f, 2.8565500e-02f,
    6.5728500e-02f, 1.3533528e-01f, 2.4935221e-01f, 4.1111229e-01f, 6.0653066e-01f,
    8.0073740e-01f, 9.4595947e-01f, 1.0000000e+00f, 9.4595947e-01f, 8.0073740e-01f,
    6.0653066e-01f, 4.1111229e-01f, 2.4935221e-01f, 1.3533528e-01f, 6.5728500e-02f,
    2.8565500e-02f, 1.1108997e-02f, 3.8659300e-03f, 1.2038700e-03f, 3.3546263e-04f
};

constexpr int BH  = 4;            // output rows per block
constexpr int NT  = 896;          // threads (14 waves); 896*3 float4 = 2688 = WC/4
constexpr int SD  = 273;          // dwords per channel plane (odd -> conflict-free)
constexpr int SDR = CC * SD;      // 5733 dwords per staged row
constexpr int NSV = BH + 2 * RAD; // 28 input rows per band

__global__ __launch_bounds__(NT)
void fused_kernel(const float* __restrict__ src, float* __restrict__ out)
{
    __shared__ unsigned int v_d[BH * SDR];   // 91728 B: staged V rows (fp16)
    __shared__ float out_row[WC];            // 43008 B: one fp32 output row

    const int tid = threadIdx.x;

    // XCD-chunked band mapping (512 blocks, 8 XCDs, 64 bands each)
    const int bid  = blockIdx.x;
    const int lin  = (bid & 7) * 64 + (bid >> 3);
    const int b    = lin >> 7;               // batch
    const int i0   = (lin & 127) * BH;       // first output row of band
    const float* sb = src + (size_t)b * IMG;

    // ---- zero pads: BH * 21 * 17 = 1428 pad dwords ----
#pragma unroll
    for (int rep = 0; rep < 2; ++rep) {
        const int item = tid + rep * NT;
        if (item < BH * 21 * 17) {
            const int rowp = item / 357;     // 21*17
            const int m    = item % 357;
            const int c    = m / 17, mm = m % 17;
            const int jd   = (mm < 8) ? mm : (256 + mm);
            v_d[rowp * SDR + c * SD + jd] = 0u;
        }
    }

    // ---- Phase V: vertical conv into registers ----
    // thread owns 3 float4 chunks at flat cols 4*tid + 3584*cch
    float acc[BH][12];
#pragma unroll
    for (int l = 0; l < BH; ++l)
#pragma unroll
        for (int e = 0; e < 12; ++e) acc[l][e] = 0.f;

#pragma unroll
    for (int st = 0; st < NSV; ++st) {
        const int r = i0 - RAD + st;
        float4 x0 = make_float4(0.f, 0.f, 0.f, 0.f);
        float4 x1 = x0, x2 = x0;
        if ((unsigned)r < (unsigned)HH) {
            const float* srow = sb + (size_t)r * WC + 4 * tid;
            x0 = *(const float4*)(srow);
            x1 = *(const float4*)(srow + 3584);
            x2 = *(const float4*)(srow + 7168);
        }
#pragma unroll
        for (int l = 0; l < BH; ++l) {
            const int t = st - l;
            if (t >= 0 && t <= 2 * RAD) {
                const float w = GW[t];       // compile-time literal
                acc[l][0]  = fmaf(w, x0.x, acc[l][0]);
                acc[l][1]  = fmaf(w, x0.y, acc[l][1]);
                acc[l][2]  = fmaf(w, x0.z, acc[l][2]);
                acc[l][3]  = fmaf(w, x0.w, acc[l][3]);
                acc[l][4]  = fmaf(w, x1.x, acc[l][4]);
                acc[l][5]  = fmaf(w, x1.y, acc[l][5]);
                acc[l][6]  = fmaf(w, x1.z, acc[l][6]);
                acc[l][7]  = fmaf(w, x1.w, acc[l][7]);
                acc[l][8]  = fmaf(w, x2.x, acc[l][8]);
                acc[l][9]  = fmaf(w, x2.y, acc[l][9]);
                acc[l][10] = fmaf(w, x2.z, acc[l][10]);
                acc[l][11] = fmaf(w, x2.w, acc[l][11]);
            }
        }
    }

    // ---- stage V rows into LDS fp16 channel-planar ----
    {
        _Float16* vh = (_Float16*)v_d;
#pragma unroll
        for (int cch = 0; cch < 3; ++cch) {
#pragma unroll
            for (int e = 0; e < 4; ++e) {
                const int ff = 4 * tid + 3584 * cch + e;
                const int ch = ff % CC, j = ff / CC;
                const int ofs = ch * (2 * SD) + 16 + j;
#pragma unroll
                for (int l = 0; l < BH; ++l)
                    vh[l * (2 * SDR) + ofs] = (_Float16)acc[l][4 * cch + e];
            }
        }
    }
    __syncthreads();

    // ---- Phase H, row-by-row: compute -> LDS out_row -> subtract+store ----
    for (int rr = 0; rr < BH; ++rr) {
        if (tid < 672) {                     // 672 = 21 ch * 32 groups of 16
            const int c  = tid % CC;
            const int j0 = (tid / CC) * 16;
            // first tap fp16 idx = 16 + j0 - 12 = j0 + 4 (even); 20 dwords
            const unsigned int* vb = v_d + rr * SDR + c * SD + (j0 + 4) / 2;
            float w[40];
#pragma unroll
            for (int m = 0; m < 20; ++m) {
                union { unsigned int u; _Float16 h[2]; } cv;
                cv.u = vb[m];
                w[2 * m]     = (float)cv.h[0];
                w[2 * m + 1] = (float)cv.h[1];
            }
#pragma unroll
            for (int k = 0; k < 16; ++k) {
                float a = 0.f;
#pragma unroll
                for (int t = 0; t < 25; ++t)
                    a = fmaf(GW[t], w[k + t], a);
                out_row[(j0 + k) * CC + c] = a;   // immediate: no reg residency
            }
        }
        __syncthreads();

        const size_t rowbase = ((size_t)b * HH + i0 + rr) * WC;
        const float4* srcv = (const float4*)(src + rowbase);
        float4*       outv = (float4*)(out + rowbase);
        const float4* olv  = (const float4*)out_row;
#pragma unroll
        for (int k2 = 0; k2 < 3; ++k2) {    // 896*3 = 2688 float4 exactly
            const int g = tid + k2 * NT;
            const float4 o = olv[g];
            const float4 s = srcv[g];
            outv[g] = make_float4(o.x - s.x, o.y - s.y, o.z - s.z, o.w - s.w);
        }
        __syncthreads();                     // out_row reused next rr
    }
}

extern "C" void kernel_launch(void* const* d_in, const int* in_sizes, int n_in,
                              void* d_out, int out_size, void* d_ws, size_t ws_size,
                              hipStream_t stream)
{
    const float* src = (const float*)d_in[0];
    float*       out = (float*)d_out;
    (void)d_ws; (void)ws_size;

    dim3 g(HH / BH * BATCH);                // 512 blocks, batch folded in
    fused_kernel<<<g, NT, 0, stream>>>(src, out);
}

// Round 6
// 220.727 us; speedup vs baseline: 4.7234x; 1.8507x over previous
//
#include <hip/hip_runtime.h>

// Gaussian blur (theta=3, truncate=4 -> r=12, 25 taps), separable, minus identity.
// src: (4, 512, 512, 21) fp32 NHWC.  out = V(H(src)) - src with zero padding.
// FUSED single kernel: block = (band of BH=4 output rows) x full width x 1 batch.
// Register-pressure-bounded design (rounds 1-5 all spilled):
//   - __launch_bounds__(NT, 1): lift default waves/EU-driven 64-VGPR cap.
//   - Phase V: 3 SEQUENTIAL chunk passes (unroll 1), each holds only
//     acc[4][4]+1 float4 (~35 live), stages to LDS fp16, reuses regs.
//   - Phase H: row-by-row (unroll 1 -> one w[40] window live, ~46 regs),
//     results written immediately to separate LDS out_row.
// LDS: v_d 91728 B + out_row 43008 B = 134736 B (1 block/CU, 14 waves).
// No global intermediate: HBM traffic = src once + out once (~176 MB).
// XCD-chunked band mapping: each XCD owns 64 contiguous bands.

#define BATCH 4
#define HH 512
#define WW 512
#define CC 21
#define WC (WW * CC)            // 10752 floats per row
#define IMG ((size_t)HH * WC)   // elems per batch image
#define RAD 12

// g(d) = exp(-d^2/18), index = d + 12 (symmetric)
__device__ static constexpr float GW[25] = {
    3.3546263e-04f, 1.2038700e-03f, 3.8659300e-03f, 1.1108997e-02f, 2.8565500e-02f,
    6.5728500e-02f, 1.3533528e-01f, 2.4935221e-01f, 4.1111229e-01f, 6.0653066e-01f,
    8.0073740e-01f, 9.4595947e-01f, 1.0000000e+00f, 9.4595947e-01f, 8.0073740e-01f,
    6.0653066e-01f, 4.1111229e-01f, 2.4935221e-01f, 1.3533528e-01f, 6.5728500e-02f,
    2.8565500e-02f, 1.1108997e-02f, 3.8659300e-03f, 1.2038700e-03f, 3.3546263e-04f
};

constexpr int BH  = 4;            // output rows per block
constexpr int NT  = 896;          // threads (14 waves); 896*3 float4 = 2688 = WC/4
constexpr int SD  = 273;          // dwords per channel plane (odd -> conflict-free)
constexpr int SDR = CC * SD;      // 5733 dwords per staged row
constexpr int NSV = BH + 2 * RAD; // 28 input rows per band

__global__ __launch_bounds__(NT, 1)
void fused_kernel(const float* __restrict__ src, float* __restrict__ out)
{
    __shared__ unsigned int v_d[BH * SDR];   // 91728 B: staged V rows (fp16)
    __shared__ float out_row[WC];            // 43008 B: one fp32 output row

    const int tid = threadIdx.x;

    // XCD-chunked band mapping (512 blocks, 8 XCDs, 64 bands each)
    const int bid  = blockIdx.x;
    const int lin  = (bid & 7) * 64 + (bid >> 3);
    const int b    = lin >> 7;               // batch
    const int i0   = (lin & 127) * BH;       // first output row of band
    const float* sb = src + (size_t)b * IMG;

    // ---- zero pads: BH * 21 * 17 = 1428 pad dwords ----
#pragma unroll
    for (int rep = 0; rep < 2; ++rep) {
        const int item = tid + rep * NT;
        if (item < BH * 21 * 17) {
            const int rowp = item / 357;     // 21*17
            const int m    = item % 357;
            const int c    = m / 17, mm = m % 17;
            const int jd   = (mm < 8) ? mm : (256 + mm);
            v_d[rowp * SDR + c * SD + jd] = 0u;
        }
    }

    // ---- Phase V: 3 sequential chunk passes, low register pressure ----
    // chunk cch covers flat cols 4*tid + 3584*cch (float4 per thread)
    _Float16* vh = (_Float16*)v_d;
#pragma unroll 1
    for (int cch = 0; cch < 3; ++cch) {
        const int ff = 4 * tid + 3584 * cch;
        const float* scol = sb + ff;

        float a0[BH], a1[BH], a2[BH], a3[BH];
#pragma unroll
        for (int l = 0; l < BH; ++l) { a0[l]=0.f; a1[l]=0.f; a2[l]=0.f; a3[l]=0.f; }

#pragma unroll
        for (int st = 0; st < NSV; ++st) {
            const int r = i0 - RAD + st;
            float4 x = make_float4(0.f, 0.f, 0.f, 0.f);
            if ((unsigned)r < (unsigned)HH)
                x = *(const float4*)(scol + (size_t)r * WC);
#pragma unroll
            for (int l = 0; l < BH; ++l) {
                const int t = st - l;
                if (t >= 0 && t <= 2 * RAD) {
                    const float w = GW[t];   // compile-time literal
                    a0[l] = fmaf(w, x.x, a0[l]);
                    a1[l] = fmaf(w, x.y, a1[l]);
                    a2[l] = fmaf(w, x.z, a2[l]);
                    a3[l] = fmaf(w, x.w, a3[l]);
                }
            }
        }

        // stage this chunk to LDS fp16 channel-planar, then recycle regs
#pragma unroll
        for (int e = 0; e < 4; ++e) {
            const int fe = ff + e;
            const int ch = fe % CC, j = fe / CC;
            const int ofs = ch * (2 * SD) + 16 + j;
#pragma unroll
            for (int l = 0; l < BH; ++l) {
                const float av = (e == 0) ? a0[l] : (e == 1) ? a1[l]
                               : (e == 2) ? a2[l] : a3[l];
                vh[l * (2 * SDR) + ofs] = (_Float16)av;
            }
        }
    }
    __syncthreads();

    // ---- Phase H, row-by-row: compute -> LDS out_row -> subtract+store ----
#pragma unroll 1
    for (int rr = 0; rr < BH; ++rr) {
        if (tid < 672) {                     // 672 = 21 ch * 32 groups of 16
            const int c  = tid % CC;
            const int j0 = (tid / CC) * 16;
            // first tap fp16 idx = 16 + j0 - 12 = j0 + 4 (even); 20 dwords
            const unsigned int* vb = v_d + rr * SDR + c * SD + (j0 + 4) / 2;
            float w[40];
#pragma unroll
            for (int m = 0; m < 20; ++m) {
                union { unsigned int u; _Float16 h[2]; } cv;
                cv.u = vb[m];
                w[2 * m]     = (float)cv.h[0];
                w[2 * m + 1] = (float)cv.h[1];
            }
#pragma unroll
            for (int k = 0; k < 16; ++k) {
                float a = 0.f;
#pragma unroll
                for (int t = 0; t < 25; ++t)
                    a = fmaf(GW[t], w[k + t], a);
                out_row[(j0 + k) * CC + c] = a;   // immediate: no reg residency
            }
        }
        __syncthreads();

        const size_t rowbase = ((size_t)b * HH + i0 + rr) * WC;
        const float4* srcv = (const float4*)(src + rowbase);
        float4*       outv = (float4*)(out + rowbase);
        const float4* olv  = (const float4*)out_row;
#pragma unroll
        for (int k2 = 0; k2 < 3; ++k2) {    // 896*3 = 2688 float4 exactly
            const int g = tid + k2 * NT;
            const float4 o = olv[g];
            const float4 s = srcv[g];
            outv[g] = make_float4(o.x - s.x, o.y - s.y, o.z - s.z, o.w - s.w);
        }
        __syncthreads();                     // out_row reused next rr
    }
}

extern "C" void kernel_launch(void* const* d_in, const int* in_sizes, int n_in,
                              void* d_out, int out_size, void* d_ws, size_t ws_size,
                              hipStream_t stream)
{
    const float* src = (const float*)d_in[0];
    float*       out = (float*)d_out;
    (void)d_ws; (void)ws_size;

    dim3 g(HH / BH * BATCH);                // 512 blocks, batch folded in
    fused_kernel<<<g, NT, 0, stream>>>(src, out);
}

// Round 7
// 190.745 us; speedup vs baseline: 5.4658x; 1.1572x over previous
//
#include <hip/hip_runtime.h>

// Gaussian blur (theta=3, truncate=4 -> r=12, 25 taps), separable, minus identity.
// src: (4, 512, 512, 21) fp32 NHWC.  out = V(H(src)) - src with zero padding.
// Two-pass (re-anchored on proven round-0 structure; fused variant was
// latency-bound at 1 block/CU and lost to phase overlap across blocks).
// Pass 1: vertical conv -> fp16 intermediate (NHWC flat) in d_ws (44 MB).
//         BH1=16 x float4 (the only accumulator shape the unroller accepts
//         without spilling). NEW: XCD-chunked block map -- each XCD owns 16
//         vertically consecutive bands x 11 col tiles, so the 24-row halo
//         overlaps between adjacent bands hit that XCD's own L2.
// Pass 2: one block per row; LDS channel-planar transpose; 25-tap conv from
//         LDS with aligned b32 reads; LDS re-transpose; coalesced float4 out.

#define BATCH 4
#define HH 512
#define WW 512
#define CC 21
#define WC (WW * CC)            // 10752 floats per row
#define IMG ((size_t)HH * WC)   // elems per batch image
#define RAD 12

// g(d) = exp(-d^2/18), index = d + 12 (symmetric)
__device__ static constexpr float GW[25] = {
    3.3546263e-04f, 1.2038700e-03f, 3.8659300e-03f, 1.1108997e-02f, 2.8565500e-02f,
    6.5728500e-02f, 1.3533528e-01f, 2.4935221e-01f, 4.1111229e-01f, 6.0653066e-01f,
    8.0073740e-01f, 9.4595947e-01f, 1.0000000e+00f, 9.4595947e-01f, 8.0073740e-01f,
    6.0653066e-01f, 4.1111229e-01f, 2.4935221e-01f, 1.3533528e-01f, 6.5728500e-02f,
    2.8565500e-02f, 1.1108997e-02f, 3.8659300e-03f, 1.2038700e-03f, 3.3546263e-04f
};

// ---------------- Pass 1: vertical ----------------
// 256 threads; thread owns 4 consecutive flat cols (float4) x BH1 output rows.
// BH1=16: 64 accumulator VGPRs -> no spill, full unroll -> literal weights.
constexpr int BH1 = 16;
constexpr int NXT = 11;                    // col tiles (11*1024 >= WC)
constexpr int NWG1 = NXT * (HH / BH1) * BATCH;   // 1408 blocks, %8 == 0

__global__ __launch_bounds__(256)
void vconv_kernel(const float* __restrict__ src, _Float16* __restrict__ v)
{
    // XCD-chunked bijective remap: xcd = wgid&7 owns 176 contiguous
    // (band-major) work items -> 16 consecutive bands x 11 tiles each.
    const int wgid = blockIdx.x;
    const int g    = (wgid & 7) * (NWG1 / 8) + (wgid >> 3);
    const int xt   = g % NXT;              // column tile
    const int band = g / NXT;              // 0..127 (batch-major)
    const int b    = band >> 5;            // batch
    const int i0   = (band & 31) * BH1;    // first output row

    const int f = xt * 1024 + threadIdx.x * 4;   // flat col (w*c)
    if (f >= WC) return;

    const float* s = src + (size_t)b * IMG + f;

    float acc[BH1][4];
#pragma unroll
    for (int p = 0; p < BH1; ++p) {
        acc[p][0] = 0.f; acc[p][1] = 0.f; acc[p][2] = 0.f; acc[p][3] = 0.f;
    }

#pragma unroll
    for (int a = 0; a < BH1 + 2 * RAD; ++a) {
        const int row = i0 - RAD + a;
        float4 x = make_float4(0.f, 0.f, 0.f, 0.f);
        if (row >= 0 && row < HH)
            x = *(const float4*)(s + (size_t)row * WC);
#pragma unroll
        for (int p = 0; p < BH1; ++p) {
            if (a - p >= 0 && a - p <= 2 * RAD) {
                const float w = GW[a - p];   // compile-time index -> literal
                acc[p][0] = fmaf(w, x.x, acc[p][0]);
                acc[p][1] = fmaf(w, x.y, acc[p][1]);
                acc[p][2] = fmaf(w, x.z, acc[p][2]);
                acc[p][3] = fmaf(w, x.w, acc[p][3]);
            }
        }
    }

    _Float16* vp = v + (size_t)b * IMG + (size_t)i0 * WC + f;
#pragma unroll
    for (int p = 0; p < BH1; ++p) {
        union { _Float16 h[4]; uint2 q; } pk;
        pk.h[0] = (_Float16)acc[p][0];
        pk.h[1] = (_Float16)acc[p][1];
        pk.h[2] = (_Float16)acc[p][2];
        pk.h[3] = (_Float16)acc[p][3];
        *(uint2*)(vp + (size_t)p * WC) = pk.q;   // 8B aligned: f%4==0
    }
}

// ---------------- Pass 2: horizontal + subtract ----------------
// One block (384 threads) per (batch, row).
// LDS phase A: v row staged channel-planar: v_d[c][jd], jd = dword (2 fp16),
//   row stride 273 dwords (odd -> conflict-free), fp16 index = 16 + j
//   (16 zero-pad halves each side absorb the j<0 / j>=512 taps).
// Compute: thread (c, j0=32*jg) reads 28 aligned dwords, 800 literal-weight FMAs.
// LDS phase B: results re-staged NHWC fp32 (aliased buffer), then coalesced
//   float4 read + src subtract + store.
constexpr int SD  = 273;   // dword stride per channel row in LDS
constexpr int NT2 = 384;

__global__ __launch_bounds__(NT2)
void hconv_kernel(const _Float16* __restrict__ v, const float* __restrict__ src,
                  float* __restrict__ out)
{
    __shared__ float out_l[WC];                 // 43008 B
    unsigned int* v_d = (unsigned int*)out_l;   // alias; uses 21*273*4 = 22932 B

    const int tid = threadIdx.x;
    const int row = blockIdx.x;
    const int b   = blockIdx.y;
    const size_t rowbase = ((size_t)b * HH + row) * WC;

    // ---- phase A: zero pads + stage v row transposed ----
    if (tid < 21 * 17) {                        // 17 pad dwords per channel
        const int c = tid / 17, m = tid % 17;
        const int jd = (m < 8) ? m : (256 + m); // dwords [0..7] and [264..272]
        v_d[c * SD + jd] = 0u;
    }
    {
        const unsigned int* vrow32 = (const unsigned int*)(v + rowbase);
        _Float16* vh = (_Float16*)v_d;
#pragma unroll
        for (int k = 0; k < 14; ++k) {
            const int g = tid + k * NT2;        // 384*14 = 5376 dwords exactly
            union { unsigned int u; _Float16 h[2]; } cv;
            cv.u = vrow32[g];
            const int f0 = 2 * g;
            const int c0 = f0 % CC, j0 = f0 / CC;
            const int f1 = f0 + 1;
            const int c1 = f1 % CC, j1 = f1 / CC;
            vh[c0 * (2 * SD) + 16 + j0] = cv.h[0];
            vh[c1 * (2 * SD) + 16 + j1] = cv.h[1];
        }
    }
    __syncthreads();

    // ---- compute: 336 active threads, each (c, j0..j0+31) ----
    float res[32];
    const bool active = tid < 21 * 16;
    int c = 0, j0 = 0;
    if (active) {
        c  = tid % CC;
        j0 = (tid / CC) * 32;
        const int base = c * SD + (j0 + 4) / 2;  // dword of fp16 idx (16+j0-12)
        float w[56];
#pragma unroll
        for (int m = 0; m < 28; ++m) {
            union { unsigned int u; _Float16 h[2]; } cv;
            cv.u = v_d[base + m];
            w[2 * m]     = (float)cv.h[0];
            w[2 * m + 1] = (float)cv.h[1];
        }
#pragma unroll
        for (int k = 0; k < 32; ++k) {
            float a = 0.f;
#pragma unroll
            for (int t = 0; t < 25; ++t)
                a = fmaf(GW[t], w[k + t], a);
            res[k] = a;
        }
    }
    __syncthreads();

    // ---- phase B: re-stage NHWC fp32 (overwrites v_d region) ----
    if (active) {
#pragma unroll
        for (int k = 0; k < 32; ++k)
            out_l[(j0 + k) * CC + c] = res[k];
    }
    __syncthreads();

    // ---- final: coalesced subtract + store ----
    const float4* srcv = (const float4*)(src + rowbase);
    float4*       outv = (float4*)(out + rowbase);
    const float4* olv  = (const float4*)out_l;
#pragma unroll
    for (int k = 0; k < 7; ++k) {               // 384*7 = 2688 float4 exactly
        const int g = tid + k * NT2;
        const float4 o = olv[g];
        const float4 s = srcv[g];
        outv[g] = make_float4(o.x - s.x, o.y - s.y, o.z - s.z, o.w - s.w);
    }
}

extern "C" void kernel_launch(void* const* d_in, const int* in_sizes, int n_in,
                              void* d_out, int out_size, void* d_ws, size_t ws_size,
                              hipStream_t stream)
{
    const float* src = (const float*)d_in[0];
    float*       out = (float*)d_out;
    _Float16*    v   = (_Float16*)d_ws;     // 4*512*10752*2 = 44 MB

    vconv_kernel<<<dim3(NWG1), 256, 0, stream>>>(src, v);   // 1408 blocks, XCD-chunked

    dim3 g2(HH, BATCH);                     // one block per (row, batch)
    hconv_kernel<<<g2, NT2, 0, stream>>>(v, src, out);
}